// Round 17
// baseline (319.991 us; speedup 1.0000x reference)
//
#include <hip/hip_runtime.h>
#include <math.h>

#define N    257     // state dim
#define AP   258     // floats per A row (cols 0..256 = S, col 257 = rhs)
#define MM   128     // rotation pairs
#define LL   512     // seq length
#define BB   4       // batch
#define NB   32      // panel width
#define U12S 226     // U12 row stride

// ws byte layout (round-14 verified, fp32 LU):
#define A_BYTE    0         // float[257*258] = 265224
#define W0_BYTE   265224    // float[257]  -> 266252
#define CXY_BYTE  266256    // float[4096] -> 282640
#define PW_BYTE   282640    // float[32*257] = 32896 -> 315536
#define U12_BYTE  315536    // float[32*226] = 28928 -> 344464
#define ST_BYTE   344464    // float[257*257] = 264196 -> 608660
// total ~609 KB (ws >= 1.31 MB)

// ---------------------------------------------------------------------------
// stage + scan in ONE dispatch (r14 verified).
// ---------------------------------------------------------------------------
__global__ __launch_bounds__(512) void stage_scan_kernel(const float* __restrict__ S,
                                                         const float* __restrict__ z0,
                                                         const float* __restrict__ x,
                                                         void* __restrict__ wsv) {
  const int tid = threadIdx.x;
  const int bid = blockIdx.x;

  if (bid < 130) {
    float* A  = (float*)((char*)wsv + A_BYTE);
    float* St = (float*)((char*)wsv + ST_BYTE);
    const int idx = bid * 512 + tid;
    if (idx < N * N) {
      const int i = idx / N, j = idx - i * N;
      A[(size_t)i * AP + j] = S[idx];
      St[idx] = S[j * N + i];          // St[d][i] = S[i][d]
    } else if (idx < N * N + N) {
      const int r = idx - N * N;
      A[(size_t)r * AP + N] = z0[r];
    }
    return;
  }

  const int wave = tid >> 6, lane = tid & 63;
  const int b    = wave >> 1, comp = wave & 1;
  const float* xp = x + ((size_t)b * LL) * 2 + comp;
  double loc[8];
  double run = 0.0;
  #pragma unroll
  for (int e = 0; e < 8; ++e) {
    run += (double)xp[(lane * 8 + e) * 2];
    loc[e] = run;
  }
  double tot = run;
  #pragma unroll
  for (int off = 1; off < 64; off <<= 1) {
    const double o = __shfl_up(tot, off);
    if (lane >= off) tot += o;
  }
  const double excl = tot - run;
  float* cp = (float*)((char*)wsv + CXY_BYTE) + ((size_t)b * LL) * 2 + comp;
  #pragma unroll
  for (int e = 0; e < 8; ++e)
    cp[(lane * 8 + e) * 2] = (float)(excl + loc[e]);
}

// ---------------------------------------------------------------------------
// panel factor (round-17): TWO Jordan steps per barrier.
// r16 evidence: float4 cut LDS issues 4x but saved only 0.5us/factor ->
// the cost is PHASE OVERHEAD (barrier + pinv/piv latency round-trip +
// publisher serial tail ~= 1650cy/step), not issue throughput. Fix: halve
// the phase count. Phase ph handles steps {j=2ph, j+1}:
//  - pivA[s] = pivot row j (fully updated), rawB[s] = row j+1 updated
//    through step j-1; both published LAST phase by threads k0+j,k0+j+1.
//  - every thread redundantly reconstructs the step-(j+1) pivot row
//    element-wise: pivrow_c = rawB[c] - fB*pivA[c], fB = rawB[j]*pinv1 —
//    bitwise identical to what thread k0+j+1 computes for itself (same
//    a-b*c fma pattern, same operands); pinv2 = 1/pivrow_{j+1} is exact
//    division -> all threads agree bitwise. NO new register array (spill
//    lesson r8/r12/r13): pivrow is a per-element temp.
//  - thread k0+j+1 applies step j only (it is step j+1's pivot row).
//  - threads k0+j+2, k0+j+3 publish their post-both-steps rows -> slot s^1.
// Checks: absmax must be EXACTLY 1.625 (else contraction mismatch ->
// revert r16); VGPR <=110 & factor <45us (else spill -> revert).
// ---------------------------------------------------------------------------
__global__ __launch_bounds__(320, 1) void panel_factor_kernel(void* __restrict__ wsv,
                                                              int k0) {
  __shared__ __align__(16) float pivA[2][NB];      // step-j pivot row (full)
  __shared__ __align__(16) float rawB[2][NB];      // row j+1, raw through j-1
  __shared__ __align__(16) float F11s[NB][NB + 4]; // 144B rows, 16B aligned
  float* A    = (float*)((char*)wsv + A_BYTE);
  float* Pw   = (float*)((char*)wsv + PW_BYTE);
  float* U12w = (float*)((char*)wsv + U12_BYTE);
  const int tid = threadIdx.x;
  const int ct  = k0 + NB;
  const int tc2 = 258 - ct;              // trailing cols incl rhs

  // ---- stage my row's panel slice into registers (L2-resident A) ----
  float r[NB];
  if (tid < N) {
    const float* Ar = A + (size_t)tid * AP + k0;
    #pragma unroll
    for (int c = 0; c < NB; c += 2) {
      const float2 v = *(const float2*)&Ar[c];
      r[c] = v.x; r[c + 1] = v.y;
    }
  }

  // ---- initial publish: rows k0 (pivot 0) and k0+1 (raw) ----
  if (tid == k0) {
    #pragma unroll
    for (int c = 0; c < NB; ++c) pivA[0][c] = r[c];
  }
  if (tid == k0 + 1) {
    #pragma unroll
    for (int c = 0; c < NB; ++c) rawB[0][c] = r[c];
  }
  __syncthreads();

  // ---- 16 phases x 2 Jordan steps ----
  #pragma unroll
  for (int ph = 0; ph < NB / 2; ++ph) {
    const int j   = 2 * ph;
    const int s   = ph & 1;
    const int prj = k0 + j;
    if (tid < N && (tid < k0 || tid > prj)) {
      const float pinv1 = 1.0f / pivA[s][j];
      const float f1 = r[j] * pinv1;
      if (tid == prj + 1) {
        // row j+1: apply step j ONLY (it is step j+1's pivot row)
        #pragma unroll
        for (int q = 0; q < NB / 4; ++q) {
          if (4 * q + 3 > j) {
            const float4 pv = *(const float4*)&pivA[s][4 * q];
            if (4 * q     > j) r[4 * q]     -= f1 * pv.x;
            if (4 * q + 1 > j) r[4 * q + 1] -= f1 * pv.y;
            if (4 * q + 2 > j) r[4 * q + 2] -= f1 * pv.z;
            r[4 * q + 3] -= f1 * pv.w;       // 4q+3 > j by outer guard
          }
        }
        r[j] = f1;
      } else {
        // apply steps j AND j+1
        const float fB    = rawB[s][j] * pinv1;                  // == row j+1's f1
        const float prj1  = rawB[s][j + 1] - fB * pivA[s][j + 1]; // pivot j+1 diag
        const float pinv2 = 1.0f / prj1;
        r[j + 1] -= f1 * pivA[s][j + 1];     // step j on element j+1
        const float f2 = r[j + 1] * pinv2;
        #pragma unroll
        for (int q = 0; q < NB / 4; ++q) {
          if (4 * q + 3 > j + 1) {
            const float4 pv = *(const float4*)&pivA[s][4 * q];
            const float4 rw = *(const float4*)&rawB[s][4 * q];
            if (4 * q > j + 1) {
              r[4 * q] -= f1 * pv.x;
              r[4 * q] -= f2 * (rw.x - fB * pv.x);
            }
            if (4 * q + 1 > j + 1) {
              r[4 * q + 1] -= f1 * pv.y;
              r[4 * q + 1] -= f2 * (rw.y - fB * pv.y);
            }
            if (4 * q + 2 > j + 1) {
              r[4 * q + 2] -= f1 * pv.z;
              r[4 * q + 2] -= f2 * (rw.z - fB * pv.z);
            }
            r[4 * q + 3] -= f1 * pv.w;       // 4q+3 > j+1 by outer guard
            r[4 * q + 3] -= f2 * (rw.w - fB * pv.w);
          }
        }
        r[j]     = f1;
        r[j + 1] = f2;
        if (ph + 1 < NB / 2) {               // publish next phase's rows
          if (tid == prj + 2) {
            #pragma unroll
            for (int c = 0; c < NB; ++c) pivA[s ^ 1][c] = r[c];
          }
          if (tid == prj + 3) {
            #pragma unroll
            for (int c = 0; c < NB; ++c) rawB[s ^ 1][c] = r[c];
          }
        }
      }
    }
    __syncthreads();
  }

  // ---- publish: pivot band -> F11s + A; other rows -> Pw (scalar) ----
  if (tid < N) {
    if (tid >= k0 && tid < ct) {
      const int fr = tid - k0;
      #pragma unroll
      for (int c = 0; c < NB; ++c) {
        F11s[fr][c] = r[c];
        A[(size_t)tid * AP + k0 + c] = r[c];   // U11/L11 for finish kernel
      }
    } else {
      #pragma unroll
      for (int t = 0; t < NB; ++t)
        Pw[(size_t)t * N + tid] = r[t];
    }
  }
  __syncthreads();                             // F11s ready

  // ---- U12 forward solve: float4 F11s reads, SEQUENTIAL fma chain
  //      (r16-verified, bit-identical to r14) ----
  if (tid < tc2) {
    float u[NB];
    #pragma unroll
    for (int jr = 0; jr < NB; ++jr)
      u[jr] = A[(size_t)(k0 + jr) * AP + ct + tid];   // coalesced across tid
    #pragma unroll
    for (int jr = 1; jr < NB; ++jr) {
      float vv = u[jr];
      #pragma unroll
      for (int q = 0; q < jr / 4; ++q) {
        const float4 fv = *(const float4*)&F11s[jr][4 * q];
        vv -= fv.x * u[4 * q];                 // sequential, same order as r14
        vv -= fv.y * u[4 * q + 1];
        vv -= fv.z * u[4 * q + 2];
        vv -= fv.w * u[4 * q + 3];
      }
      #pragma unroll
      for (int t = (jr / 4) * 4; t < jr; ++t)
        vv -= F11s[jr][t] * u[t];              // remainder, scalar
      u[jr] = vv;
    }
    #pragma unroll
    for (int jr = 0; jr < NB; ++jr) {
      U12w[jr * U12S + tid] = u[jr];
      A[(size_t)(k0 + jr) * AP + ct + tid] = u[jr];
    }
  }
}

// ---------------------------------------------------------------------------
// panel update (rank-32 Jordan GEMM), r14-verified fp32 body (p = 0..6).
// ---------------------------------------------------------------------------
__global__ __launch_bounds__(256) void panel_update_kernel(void* __restrict__ wsv,
                                                           int k0, int tc2) {
  __shared__ float Pl[NB][NB + 1];
  __shared__ __align__(16) float Ul[NB][66];
  float* A = (float*)((char*)wsv + A_BYTE);
  const float* Pw   = (const float*)((const char*)wsv + PW_BYTE);
  const float* U12w = (const float*)((const char*)wsv + U12_BYTE);
  const int tid = threadIdx.x;
  const int ct  = k0 + NB;
  const int rb0 = blockIdx.x * 32;
  const int c0  = blockIdx.y * 64;

  for (int i = tid; i < 32 * 32; i += 256) {
    const int t = i >> 5, rr = i & 31;
    const int rb = rb0 + rr;
    const int gr = (rb < k0) ? rb : rb + NB;
    Pl[t][rr] = (rb < 225) ? Pw[(size_t)t * N + gr] : 0.0f;
  }
  for (int i = tid; i < 32 * 64; i += 256) {
    const int t = i >> 6, c = i & 63;
    Ul[t][c] = (c0 + c < tc2) ? U12w[t * U12S + c0 + c] : 0.0f;
  }
  __syncthreads();

  const int tr  = tid >> 4;          // 0..15 -> rows tr*2 .. +1
  const int tcx = (tid & 15) * 4;    // cols tcx .. +3
  float acc[2][4];
  #pragma unroll
  for (int rr = 0; rr < 2; ++rr) {
    const int rb = rb0 + tr * 2 + rr;
    const int gr = (rb < k0) ? rb : rb + NB;
    #pragma unroll
    for (int c = 0; c < 4; ++c)
      acc[rr][c] = (rb < 225 && (c0 + tcx + c) < tc2)
                 ? A[(size_t)gr * AP + ct + c0 + tcx + c] : 0.0f;
  }
  #pragma unroll
  for (int t = 0; t < NB; ++t) {
    const float p0 = Pl[t][tr * 2], p1 = Pl[t][tr * 2 + 1];
    const float2 u0 = *(const float2*)&Ul[t][tcx];
    const float2 u1 = *(const float2*)&Ul[t][tcx + 2];
    acc[0][0] -= p0 * u0.x; acc[0][1] -= p0 * u0.y;
    acc[0][2] -= p0 * u1.x; acc[0][3] -= p0 * u1.y;
    acc[1][0] -= p1 * u0.x; acc[1][1] -= p1 * u0.y;
    acc[1][2] -= p1 * u1.x; acc[1][3] -= p1 * u1.y;
  }
  #pragma unroll
  for (int rr = 0; rr < 2; ++rr) {
    const int rb = rb0 + tr * 2 + rr;
    const int gr = (rb < k0) ? rb : rb + NB;
    #pragma unroll
    for (int c = 0; c < 4; ++c)
      if (rb < 225 && (c0 + tcx + c) < tc2)
        A[(size_t)gr * AP + ct + c0 + tcx + c] = acc[rr][c];
  }
}

// ---------------------------------------------------------------------------
// last: update(p=7) (225 rows x 2 cols, rank-32) + finish back-substs
// (r14-verified fp32 body).
// ---------------------------------------------------------------------------
__global__ __launch_bounds__(256) void last_kernel(void* __restrict__ wsv) {
  __shared__ float xs[N];
  __shared__ float rr[256];
  float* A = (float*)((char*)wsv + A_BYTE);
  const float* Pw   = (const float*)((const char*)wsv + PW_BYTE);
  const float* U12w = (const float*)((const char*)wsv + U12_BYTE);
  float* w0f = (float*)((char*)wsv + W0_BYTE);
  const int tid = threadIdx.x;

  // update(7): rows [0,224) U {256}, cols {256, 257}
  for (int idx = tid; idx < 225 * 2; idx += 256) {
    const int rb = idx >> 1, c = idx & 1;
    const int gr = (rb < 224) ? rb : 256;
    float acc = A[(size_t)gr * AP + 256 + c];
    #pragma unroll
    for (int t = 0; t < NB; ++t)
      acc -= Pw[(size_t)t * N + gr] * U12w[t * U12S + c];
    A[(size_t)gr * AP + 256 + c] = acc;
  }
  __threadfence_block();
  __syncthreads();

  // finish (r6-verified body, fp32)
  if (tid == 0) xs[256] = A[256 * AP + 257] / A[256 * AP + 256];
  __syncthreads();
  const float x256 = xs[256];
  rr[tid] = A[(size_t)tid * AP + 257] - A[(size_t)tid * AP + 256] * x256;
  __syncthreads();
  const int fk0 = tid & ~31;
  const int fs  = tid & 31;
  for (int j = 31; j >= 0; --j) {
    if (fs == j) xs[fk0 + j] = rr[fk0 + j] / A[(size_t)(fk0 + j) * AP + (fk0 + j)];
    __syncthreads();
    if (fs < j) rr[fk0 + fs] -= A[(size_t)(fk0 + fs) * AP + (fk0 + j)] * xs[fk0 + j];
    __syncthreads();
  }
  w0f[tid] = xs[tid];
  if (tid == 0) w0f[256] = xs[256];
}

// ---------------------------------------------------------------------------
// combine: out[(b,l), i] = sum_d St[d, i] * W[(b,l), d]   (round-4 verified)
// ---------------------------------------------------------------------------
#define NL 8
__global__ __launch_bounds__(320) void combine_kernel(const float* __restrict__ S,
                                                      const float* __restrict__ om,
                                                      const void* __restrict__ wsv,
                                                      float* __restrict__ out) {
  const int tid = threadIdx.x;
  const int b  = blockIdx.y;
  const int l0 = blockIdx.x * NL;
  const float* w0  = (const float*)((const char*)wsv + W0_BYTE);
  const float* cxy = (const float*)((const char*)wsv + CXY_BYTE);
  const float* St  = (const float*)((const char*)wsv + ST_BYTE);
  __shared__ __align__(16) float Wl[N][NL];
  __shared__ float omsh[2 * MM];
  __shared__ float cxs[NL], cys[NL];

  for (int idx = tid; idx < 2 * MM; idx += 320) omsh[idx] = om[idx];
  if (tid < NL) {
    cxs[tid] = cxy[((size_t)(b * LL) + l0 + tid) * 2];
    cys[tid] = cxy[((size_t)(b * LL) + l0 + tid) * 2 + 1];
  }
  __syncthreads();

  for (int idx = tid; idx < NL * N; idx += 320) {
    const int d = idx >> 3;
    const int r = idx & 7;
    float v;
    if (d == 0) {
      v = w0[0];
    } else {
      const int m = (d - 1) >> 1;
      const int pq = 2 * m + 1;
      const float t = cxs[r] * omsh[2 * m] + cys[r] * omsh[2 * m + 1];
      float s, c;
      sincosf(t, &s, &c);
      const float a0 = w0[pq], a1 = w0[pq + 1];
      v = (d & 1) ? (c * a0 - s * a1) : (s * a0 + c * a1);
    }
    Wl[d][r] = v;
  }
  __syncthreads();

  const int i = tid;
  if (i < N) {
    float acc[NL];
    #pragma unroll
    for (int r = 0; r < NL; ++r) acc[r] = 0.0f;
    #pragma unroll 8
    for (int d = 0; d < N; ++d) {
      const float stv = St[(size_t)d * N + i];
      const float4 wa = *(const float4*)&Wl[d][0];
      const float4 wb = *(const float4*)&Wl[d][4];
      acc[0] += stv * wa.x; acc[1] += stv * wa.y;
      acc[2] += stv * wa.z; acc[3] += stv * wa.w;
      acc[4] += stv * wb.x; acc[5] += stv * wb.y;
      acc[6] += stv * wb.z; acc[7] += stv * wb.w;
    }
    const size_t base = (size_t)(b * LL + l0) * N + i;
    #pragma unroll
    for (int r = 0; r < NL; ++r) out[base + (size_t)r * N] = acc[r];
    if (l0 + NL == LL) {
      out[(size_t)BB * LL * N + (size_t)b * N + i] = acc[NL - 1];
    }
  }
}

extern "C" void kernel_launch(void* const* d_in, const int* in_sizes, int n_in,
                              void* d_out, int out_size, void* d_ws, size_t ws_size,
                              hipStream_t stream) {
  const float* x  = (const float*)d_in[0];   // (B, L, 2)
  const float* z0 = (const float*)d_in[1];   // (D,)
  const float* om = (const float*)d_in[2];   // (M, 2)
  const float* S  = (const float*)d_in[3];   // (D, D)
  float* out = (float*)d_out;                // outputs (B,L,D) then z_final (B,D)

  hipLaunchKernelGGL(stage_scan_kernel, dim3(131), dim3(512), 0, stream, S, z0, x, d_ws);
  for (int p = 0; p < 8; ++p) {
    const int k0  = p * NB;
    const int tc2 = 258 - (k0 + NB);
    hipLaunchKernelGGL(panel_factor_kernel, dim3(1), dim3(320), 0, stream, d_ws, k0);
    if (p < 7)
      hipLaunchKernelGGL(panel_update_kernel, dim3(8, (tc2 + 63) / 64), dim3(256),
                         0, stream, d_ws, k0, tc2);
  }
  hipLaunchKernelGGL(last_kernel, dim3(1), dim3(256), 0, stream, d_ws);
  hipLaunchKernelGGL(combine_kernel, dim3(LL / NL, BB), dim3(320), 0, stream, S, om, d_ws, out);
}

// Round 18
// 296.349 us; speedup vs baseline: 1.0798x; 1.0798x over previous
//
#include <hip/hip_runtime.h>
#include <math.h>

#define N    257     // state dim
#define AP   258     // floats per A row (cols 0..256 = S, col 257 = rhs)
#define MM   128     // rotation pairs
#define LL   512     // seq length
#define BB   4       // batch
#define NB   32      // panel width
#define U12S 226     // U12 row stride

// ws byte layout (round-14 verified, fp32 LU):
#define A_BYTE    0         // float[257*258] = 265224
#define W0_BYTE   265224    // float[257]  -> 266252
#define CXY_BYTE  266256    // float[4096] -> 282640
#define PW_BYTE   282640    // float[32*257] = 32896 -> 315536
#define U12_BYTE  315536    // float[32*226] = 28928 -> 344464
#define ST_BYTE   344464    // float[257*257] = 264196 -> 608660
// total ~609 KB (ws >= 1.31 MB)

// ---------------------------------------------------------------------------
// stage + scan in ONE dispatch (r14 verified).
// ---------------------------------------------------------------------------
__global__ __launch_bounds__(512) void stage_scan_kernel(const float* __restrict__ S,
                                                         const float* __restrict__ z0,
                                                         const float* __restrict__ x,
                                                         void* __restrict__ wsv) {
  const int tid = threadIdx.x;
  const int bid = blockIdx.x;

  if (bid < 130) {
    float* A  = (float*)((char*)wsv + A_BYTE);
    float* St = (float*)((char*)wsv + ST_BYTE);
    const int idx = bid * 512 + tid;
    if (idx < N * N) {
      const int i = idx / N, j = idx - i * N;
      A[(size_t)i * AP + j] = S[idx];
      St[idx] = S[j * N + i];          // St[d][i] = S[i][d]
    } else if (idx < N * N + N) {
      const int r = idx - N * N;
      A[(size_t)r * AP + N] = z0[r];
    }
    return;
  }

  const int wave = tid >> 6, lane = tid & 63;
  const int b    = wave >> 1, comp = wave & 1;
  const float* xp = x + ((size_t)b * LL) * 2 + comp;
  double loc[8];
  double run = 0.0;
  #pragma unroll
  for (int e = 0; e < 8; ++e) {
    run += (double)xp[(lane * 8 + e) * 2];
    loc[e] = run;
  }
  double tot = run;
  #pragma unroll
  for (int off = 1; off < 64; off <<= 1) {
    const double o = __shfl_up(tot, off);
    if (lane >= off) tot += o;
  }
  const double excl = tot - run;
  float* cp = (float*)((char*)wsv + CXY_BYTE) + ((size_t)b * LL) * 2 + comp;
  #pragma unroll
  for (int e = 0; e < 8; ++e)
    cp[(lane * 8 + e) * 2] = (float)(excl + loc[e]);
}

// ---------------------------------------------------------------------------
// panel factor (r16 verified): fp32 register-resident Jordan; float4 applied
// to LOADS ONLY, operation order bit-identical to r14 (absmax 1.625 margin).
// Factor-structure history: r12 vec-LDS (spill), r13 hybrid-shfl (spill),
// r15 reassoc (absmax fail), r16 float4-loads (pass, -0.5us), r17 2-step
// phases (pass, +3us/factor). This body is the structural floor: ~650cy per
// pivot step vs ~450cy hard bound (LDS latency + barrier + publisher chain).
// ---------------------------------------------------------------------------
__global__ __launch_bounds__(320, 1) void panel_factor_kernel(void* __restrict__ wsv,
                                                              int k0) {
  __shared__ __align__(16) float piv[2][NB];       // 128B rows, 16B aligned
  __shared__ float pinvs[2];
  __shared__ __align__(16) float F11s[NB][NB + 4]; // 144B rows, 16B aligned
  float* A    = (float*)((char*)wsv + A_BYTE);
  float* Pw   = (float*)((char*)wsv + PW_BYTE);
  float* U12w = (float*)((char*)wsv + U12_BYTE);
  const int tid = threadIdx.x;
  const int ct  = k0 + NB;
  const int tc2 = 258 - ct;              // trailing cols incl rhs

  // ---- stage my row's panel slice into registers (L2-resident A) ----
  float r[NB];
  if (tid < N) {
    const float* Ar = A + (size_t)tid * AP + k0;
    #pragma unroll
    for (int c = 0; c < NB; c += 2) {
      const float2 v = *(const float2*)&Ar[c];
      r[c] = v.x; r[c + 1] = v.y;
    }
  }

  // ---- pre-step: pivot row k0 publishes itself (scalar stores) ----
  if (tid == k0) {
    #pragma unroll
    for (int c = 0; c < NB; ++c) piv[0][c] = r[c];
    pinvs[0] = 1.0f / r[0];
  }
  __syncthreads();

  // ---- 32 Jordan steps; pivot row via FLOAT4 LDS broadcast,
  //      per-element updates (bit-identical to r14) ----
  #pragma unroll
  for (int j = 0; j < NB; ++j) {
    const int pr = k0 + j;
    const int bsel = j & 1;
    if (tid < N && (tid < k0 || tid > pr)) {   // frozen: pivot rows k0..pr
      const float f = r[j] * pinvs[bsel];
      #pragma unroll
      for (int q = 0; q < NB / 4; ++q) {
        if (4 * q + 3 > j) {                   // quad has a live column
          const float4 pv = *(const float4*)&piv[bsel][4 * q];
          if (4 * q     > j) r[4 * q]     -= f * pv.x;   // compile-time guards
          if (4 * q + 1 > j) r[4 * q + 1] -= f * pv.y;
          if (4 * q + 2 > j) r[4 * q + 2] -= f * pv.z;
          r[4 * q + 3] -= f * pv.w;            // 4q+3 > j by outer guard
        }
      }
      r[j] = f;
      if (j + 1 < NB && tid == pr + 1) {       // publish next pivot row (scalar)
        #pragma unroll
        for (int c = 0; c < NB; ++c)
          if (c > j) piv[bsel ^ 1][c] = r[c];
        pinvs[bsel ^ 1] = 1.0f / r[j + 1];
      }
    }
    __syncthreads();
  }

  // ---- publish: pivot band -> F11s + A; other rows -> Pw (scalar) ----
  if (tid < N) {
    if (tid >= k0 && tid < ct) {
      const int fr = tid - k0;
      #pragma unroll
      for (int c = 0; c < NB; ++c) {
        F11s[fr][c] = r[c];
        A[(size_t)tid * AP + k0 + c] = r[c];   // U11/L11 for finish kernel
      }
    } else {
      #pragma unroll
      for (int t = 0; t < NB; ++t)
        Pw[(size_t)t * N + tid] = r[t];
    }
  }
  __syncthreads();                             // F11s ready

  // ---- U12 forward solve: float4 F11s reads, SEQUENTIAL fma chain
  //      (r14's exact operation order -> bit-identical) ----
  if (tid < tc2) {
    float u[NB];
    #pragma unroll
    for (int jr = 0; jr < NB; ++jr)
      u[jr] = A[(size_t)(k0 + jr) * AP + ct + tid];   // coalesced across tid
    #pragma unroll
    for (int jr = 1; jr < NB; ++jr) {
      float vv = u[jr];
      #pragma unroll
      for (int q = 0; q < jr / 4; ++q) {
        const float4 fv = *(const float4*)&F11s[jr][4 * q];
        vv -= fv.x * u[4 * q];                 // sequential, same order as r14
        vv -= fv.y * u[4 * q + 1];
        vv -= fv.z * u[4 * q + 2];
        vv -= fv.w * u[4 * q + 3];
      }
      #pragma unroll
      for (int t = (jr / 4) * 4; t < jr; ++t)
        vv -= F11s[jr][t] * u[t];              // remainder, scalar
      u[jr] = vv;
    }
    #pragma unroll
    for (int jr = 0; jr < NB; ++jr) {
      U12w[jr * U12S + tid] = u[jr];
      A[(size_t)(k0 + jr) * AP + ct + tid] = u[jr];
    }
  }
}

// ---------------------------------------------------------------------------
// panel update (rank-32 Jordan GEMM), r14-verified fp32 body (p = 0..6).
// ---------------------------------------------------------------------------
__global__ __launch_bounds__(256) void panel_update_kernel(void* __restrict__ wsv,
                                                           int k0, int tc2) {
  __shared__ float Pl[NB][NB + 1];
  __shared__ __align__(16) float Ul[NB][66];
  float* A = (float*)((char*)wsv + A_BYTE);
  const float* Pw   = (const float*)((const char*)wsv + PW_BYTE);
  const float* U12w = (const float*)((const char*)wsv + U12_BYTE);
  const int tid = threadIdx.x;
  const int ct  = k0 + NB;
  const int rb0 = blockIdx.x * 32;
  const int c0  = blockIdx.y * 64;

  for (int i = tid; i < 32 * 32; i += 256) {
    const int t = i >> 5, rr = i & 31;
    const int rb = rb0 + rr;
    const int gr = (rb < k0) ? rb : rb + NB;
    Pl[t][rr] = (rb < 225) ? Pw[(size_t)t * N + gr] : 0.0f;
  }
  for (int i = tid; i < 32 * 64; i += 256) {
    const int t = i >> 6, c = i & 63;
    Ul[t][c] = (c0 + c < tc2) ? U12w[t * U12S + c0 + c] : 0.0f;
  }
  __syncthreads();

  const int tr  = tid >> 4;          // 0..15 -> rows tr*2 .. +1
  const int tcx = (tid & 15) * 4;    // cols tcx .. +3
  float acc[2][4];
  #pragma unroll
  for (int rr = 0; rr < 2; ++rr) {
    const int rb = rb0 + tr * 2 + rr;
    const int gr = (rb < k0) ? rb : rb + NB;
    #pragma unroll
    for (int c = 0; c < 4; ++c)
      acc[rr][c] = (rb < 225 && (c0 + tcx + c) < tc2)
                 ? A[(size_t)gr * AP + ct + c0 + tcx + c] : 0.0f;
  }
  #pragma unroll
  for (int t = 0; t < NB; ++t) {
    const float p0 = Pl[t][tr * 2], p1 = Pl[t][tr * 2 + 1];
    const float2 u0 = *(const float2*)&Ul[t][tcx];
    const float2 u1 = *(const float2*)&Ul[t][tcx + 2];
    acc[0][0] -= p0 * u0.x; acc[0][1] -= p0 * u0.y;
    acc[0][2] -= p0 * u1.x; acc[0][3] -= p0 * u1.y;
    acc[1][0] -= p1 * u0.x; acc[1][1] -= p1 * u0.y;
    acc[1][2] -= p1 * u1.x; acc[1][3] -= p1 * u1.y;
  }
  #pragma unroll
  for (int rr = 0; rr < 2; ++rr) {
    const int rb = rb0 + tr * 2 + rr;
    const int gr = (rb < k0) ? rb : rb + NB;
    #pragma unroll
    for (int c = 0; c < 4; ++c)
      if (rb < 225 && (c0 + tcx + c) < tc2)
        A[(size_t)gr * AP + ct + c0 + tcx + c] = acc[rr][c];
  }
}

// ---------------------------------------------------------------------------
// last: update(p=7) (225 rows x 2 cols, rank-32) + finish back-substs
// (r14-verified fp32 body).
// ---------------------------------------------------------------------------
__global__ __launch_bounds__(256) void last_kernel(void* __restrict__ wsv) {
  __shared__ float xs[N];
  __shared__ float rr[256];
  float* A = (float*)((char*)wsv + A_BYTE);
  const float* Pw   = (const float*)((const char*)wsv + PW_BYTE);
  const float* U12w = (const float*)((const char*)wsv + U12_BYTE);
  float* w0f = (float*)((char*)wsv + W0_BYTE);
  const int tid = threadIdx.x;

  // update(7): rows [0,224) U {256}, cols {256, 257}
  for (int idx = tid; idx < 225 * 2; idx += 256) {
    const int rb = idx >> 1, c = idx & 1;
    const int gr = (rb < 224) ? rb : 256;
    float acc = A[(size_t)gr * AP + 256 + c];
    #pragma unroll
    for (int t = 0; t < NB; ++t)
      acc -= Pw[(size_t)t * N + gr] * U12w[t * U12S + c];
    A[(size_t)gr * AP + 256 + c] = acc;
  }
  __threadfence_block();
  __syncthreads();

  // finish (r6-verified body, fp32)
  if (tid == 0) xs[256] = A[256 * AP + 257] / A[256 * AP + 256];
  __syncthreads();
  const float x256 = xs[256];
  rr[tid] = A[(size_t)tid * AP + 257] - A[(size_t)tid * AP + 256] * x256;
  __syncthreads();
  const int fk0 = tid & ~31;
  const int fs  = tid & 31;
  for (int j = 31; j >= 0; --j) {
    if (fs == j) xs[fk0 + j] = rr[fk0 + j] / A[(size_t)(fk0 + j) * AP + (fk0 + j)];
    __syncthreads();
    if (fs < j) rr[fk0 + fs] -= A[(size_t)(fk0 + fs) * AP + (fk0 + j)] * xs[fk0 + j];
    __syncthreads();
  }
  w0f[tid] = xs[tid];
  if (tid == 0) w0f[256] = xs[256];
}

// ---------------------------------------------------------------------------
// combine: out[(b,l), i] = sum_d St[d, i] * W[(b,l), d]   (round-4 verified)
// ---------------------------------------------------------------------------
#define NL 8
__global__ __launch_bounds__(320) void combine_kernel(const float* __restrict__ S,
                                                      const float* __restrict__ om,
                                                      const void* __restrict__ wsv,
                                                      float* __restrict__ out) {
  const int tid = threadIdx.x;
  const int b  = blockIdx.y;
  const int l0 = blockIdx.x * NL;
  const float* w0  = (const float*)((const char*)wsv + W0_BYTE);
  const float* cxy = (const float*)((const char*)wsv + CXY_BYTE);
  const float* St  = (const float*)((const char*)wsv + ST_BYTE);
  __shared__ __align__(16) float Wl[N][NL];
  __shared__ float omsh[2 * MM];
  __shared__ float cxs[NL], cys[NL];

  for (int idx = tid; idx < 2 * MM; idx += 320) omsh[idx] = om[idx];
  if (tid < NL) {
    cxs[tid] = cxy[((size_t)(b * LL) + l0 + tid) * 2];
    cys[tid] = cxy[((size_t)(b * LL) + l0 + tid) * 2 + 1];
  }
  __syncthreads();

  for (int idx = tid; idx < NL * N; idx += 320) {
    const int d = idx >> 3;
    const int r = idx & 7;
    float v;
    if (d == 0) {
      v = w0[0];
    } else {
      const int m = (d - 1) >> 1;
      const int pq = 2 * m + 1;
      const float t = cxs[r] * omsh[2 * m] + cys[r] * omsh[2 * m + 1];
      float s, c;
      sincosf(t, &s, &c);
      const float a0 = w0[pq], a1 = w0[pq + 1];
      v = (d & 1) ? (c * a0 - s * a1) : (s * a0 + c * a1);
    }
    Wl[d][r] = v;
  }
  __syncthreads();

  const int i = tid;
  if (i < N) {
    float acc[NL];
    #pragma unroll
    for (int r = 0; r < NL; ++r) acc[r] = 0.0f;
    #pragma unroll 8
    for (int d = 0; d < N; ++d) {
      const float stv = St[(size_t)d * N + i];
      const float4 wa = *(const float4*)&Wl[d][0];
      const float4 wb = *(const float4*)&Wl[d][4];
      acc[0] += stv * wa.x; acc[1] += stv * wa.y;
      acc[2] += stv * wa.z; acc[3] += stv * wa.w;
      acc[4] += stv * wb.x; acc[5] += stv * wb.y;
      acc[6] += stv * wb.z; acc[7] += stv * wb.w;
    }
    const size_t base = (size_t)(b * LL + l0) * N + i;
    #pragma unroll
    for (int r = 0; r < NL; ++r) out[base + (size_t)r * N] = acc[r];
    if (l0 + NL == LL) {
      out[(size_t)BB * LL * N + (size_t)b * N + i] = acc[NL - 1];
    }
  }
}

extern "C" void kernel_launch(void* const* d_in, const int* in_sizes, int n_in,
                              void* d_out, int out_size, void* d_ws, size_t ws_size,
                              hipStream_t stream) {
  const float* x  = (const float*)d_in[0];   // (B, L, 2)
  const float* z0 = (const float*)d_in[1];   // (D,)
  const float* om = (const float*)d_in[2];   // (M, 2)
  const float* S  = (const float*)d_in[3];   // (D, D)
  float* out = (float*)d_out;                // outputs (B,L,D) then z_final (B,D)

  hipLaunchKernelGGL(stage_scan_kernel, dim3(131), dim3(512), 0, stream, S, z0, x, d_ws);
  for (int p = 0; p < 8; ++p) {
    const int k0  = p * NB;
    const int tc2 = 258 - (k0 + NB);
    hipLaunchKernelGGL(panel_factor_kernel, dim3(1), dim3(320), 0, stream, d_ws, k0);
    if (p < 7)
      hipLaunchKernelGGL(panel_update_kernel, dim3(8, (tc2 + 63) / 64), dim3(256),
                         0, stream, d_ws, k0, tc2);
  }
  hipLaunchKernelGGL(last_kernel, dim3(1), dim3(256), 0, stream, d_ws);
  hipLaunchKernelGGL(combine_kernel, dim3(LL / NL, BB), dim3(320), 0, stream, S, om, d_ws, out);
}